// Round 1
// baseline (62.789 us; speedup 1.0000x reference)
//
#include <hip/hip_runtime.h>

// Reference collapses: top_k takes ALL K=64 indices (max_chunks == K), and
// mean over the retrieved chunks is permutation-invariant. Output is simply
// mean(knowledge, axis=0) broadcast to [B, S, E]. Query is irrelevant.

#define E_DIM 512
#define K_DIM 64

// Kernel 1: column means of knowledge [64, 512] -> ws[512]
__global__ void knr_colmean_kernel(const float* __restrict__ knowledge,
                                   float* __restrict__ mean_out) {
    int e = threadIdx.x;  // 512 threads, one per column
    float s = 0.0f;
#pragma unroll
    for (int k = 0; k < K_DIM; ++k) {
        s += knowledge[k * E_DIM + e];
    }
    mean_out[e] = s * (1.0f / K_DIM);
}

// Kernel 2: broadcast mean vector to out [B*S, E] as float4 stores.
// total_f4 = B*S*E/4; each thread writes one float4.
__global__ void knr_broadcast_kernel(const float* __restrict__ mean_in,
                                     float4* __restrict__ out,
                                     int total_f4) {
    int idx = blockIdx.x * blockDim.x + threadIdx.x;
    if (idx >= total_f4) return;
    const float4* mean4 = (const float4*)mean_in;
    // E_DIM/4 = 128 float4 per output row; row-position is idx & 127
    out[idx] = mean4[idx & (E_DIM / 4 - 1)];
}

extern "C" void kernel_launch(void* const* d_in, const int* in_sizes, int n_in,
                              void* d_out, int out_size, void* d_ws, size_t ws_size,
                              hipStream_t stream) {
    // d_in[0] = query_embedding [4,1024,512] fp32 (unused — see analysis above)
    // d_in[1] = knowledge [64,512] fp32
    const float* knowledge = (const float*)d_in[1];
    float* out = (float*)d_out;
    float* mean_ws = (float*)d_ws;  // 512 floats

    knr_colmean_kernel<<<1, E_DIM, 0, stream>>>(knowledge, mean_ws);

    int total_f4 = out_size / 4;  // 4*1024*512 / 4 = 524288
    int block = 256;
    int grid = (total_f4 + block - 1) / block;  // 2048
    knr_broadcast_kernel<<<grid, block, 0, stream>>>(mean_ws, (float4*)out, total_f4);
}

// Round 2
// 61.407 us; speedup vs baseline: 1.0225x; 1.0225x over previous
//
#include <hip/hip_runtime.h>

// Reference collapses: top_k takes ALL K=64 indices (max_chunks == K), and
// mean over retrieved chunks is permutation-invariant. Output is simply
// mean(knowledge, axis=0) broadcast to [B, S, E]. Query is irrelevant.
//
// Fused single kernel: each thread's set of output float4 slots all share the
// same E-column group (grid stride 65536 f4 is a multiple of E/4 = 128), so
// the thread computes its one mean-float4 in registers (knowledge is 128 KB,
// L1/L2-resident, broadcast across the 512 threads sharing a column group),
// then writes its 8 broadcast stores. No LDS, no barriers, no workspace.

#define E_DIM 512
#define K_DIM 64
#define NF4   (E_DIM / 4)        // 128 float4 per row
#define BLOCKS 256
#define TPB    256

__global__ void __launch_bounds__(TPB)
knr_fused_kernel(const float4* __restrict__ knowledge4,  // [64 * 128] float4
                 float4* __restrict__ out,               // [B*S*E/4] float4
                 int total_f4) {
    const int tid = blockIdx.x * TPB + threadIdx.x;      // 0 .. 65535
    const int c = tid & (NF4 - 1);                       // this thread's f4 column

    // Accumulate column mean over the 64 knowledge rows (all independent loads).
    float4 s = make_float4(0.f, 0.f, 0.f, 0.f);
#pragma unroll
    for (int k = 0; k < K_DIM; ++k) {
        float4 v = knowledge4[k * NF4 + c];
        s.x += v.x; s.y += v.y; s.z += v.z; s.w += v.w;
    }
    const float inv = 1.0f / K_DIM;
    s.x *= inv; s.y *= inv; s.z *= inv; s.w *= inv;

    // Grid-stride broadcast stores; stride (BLOCKS*TPB) % NF4 == 0 keeps the
    // column invariant per thread.
    const int stride = BLOCKS * TPB;
    for (int i = tid; i < total_f4; i += stride) {
        out[i] = s;
    }
}

extern "C" void kernel_launch(void* const* d_in, const int* in_sizes, int n_in,
                              void* d_out, int out_size, void* d_ws, size_t ws_size,
                              hipStream_t stream) {
    // d_in[0] = query_embedding [4,1024,512] fp32 (unused — see analysis above)
    // d_in[1] = knowledge [64,512] fp32
    const float4* knowledge4 = (const float4*)d_in[1];
    float4* out = (float4*)d_out;
    int total_f4 = out_size / 4;  // 524288

    knr_fused_kernel<<<BLOCKS, TPB, 0, stream>>>(knowledge4, out, total_f4);
}